// Round 1
// baseline (269.487 us; speedup 1.0000x reference)
//
#include <hip/hip_runtime.h>
#include <math.h>

// ---------------- device-global folded operators -------------------------
// g_W[b][c][a(pad 24)] = sum over TP paths of w_tp[i]*alpha_i*CG[a,b,c]
// g_M[k][a][c(pad 24)] = sum over AGG paths of w_agg[i]*alpha_i*sum_b SH[k,b]*CG[a,b,c]
__device__ __align__(16) float g_W[22 * 22 * 24];
__device__ __align__(16) float g_M[4 * 22 * 24];

__constant__ double c_fact[20] = {
    1.0, 1.0, 2.0, 6.0, 24.0, 120.0, 720.0, 5040.0, 40320.0, 362880.0,
    3628800.0, 39916800.0, 479001600.0, 6227020800.0, 87178291200.0,
    1307674368000.0, 20922789888000.0, 355687428096000.0,
    6402373705728000.0, 121645100408832000.0};

__device__ double cgd(int j1, int m1, int j2, int m2, int j3, int m3) {
  if (m1 + m2 != m3) return 0.0;
  double pre = (double)(2 * j3 + 1) * c_fact[j1 + j2 - j3] * c_fact[j1 - j2 + j3] *
               c_fact[-j1 + j2 + j3] / c_fact[j1 + j2 + j3 + 1];
  pre *= c_fact[j1 + m1] * c_fact[j1 - m1] * c_fact[j2 + m2] * c_fact[j2 - m2] *
         c_fact[j3 + m3] * c_fact[j3 - m3];
  int kmin = max(0, max(j2 - j3 - m1, j1 - j3 + m2));
  int kmax = min(j1 + j2 - j3, min(j1 - m1, j2 + m2));
  double s = 0.0;
  for (int k = kmin; k <= kmax; ++k) {
    double d = c_fact[k] * c_fact[j1 + j2 - j3 - k] * c_fact[j1 - m1 - k] *
               c_fact[j2 + m2 - k] * c_fact[j3 - j2 + m1 + k] * c_fact[j3 - j1 - m2 + k];
    s += ((k & 1) ? -1.0 : 1.0) / d;
  }
  return sqrt(pre) * s;
}

__device__ double wstd(int l1, int l2, int l3, int i, int j, int k) {
  int m1 = i - l1, m2 = j - l2, m3 = k - l3;
  if (m1 + m2 + m3 != 0) return 0.0;
  int e = l1 - l2 - m3;
  double sgn = (e & 1) ? -1.0 : 1.0;
  return sgn / sqrt((double)(2 * l3 + 1)) * cgd(l1, m1, l2, m2, l3, -m3);
}

// q-matrix row (change-of-basis real<->complex SH), WITHOUT the (-i)^l factor
__device__ int qrow(int l, int a, int idx[2], double vr[2], double vi[2]) {
  const double s2 = 0.70710678118654752440;
  int m = a - l;
  if (m == 0) { idx[0] = l; vr[0] = 1.0; vi[0] = 0.0; return 1; }
  if (m > 0) {
    idx[0] = l + m; vr[0] = (m & 1) ? -s2 : s2; vi[0] = 0.0;
    idx[1] = l - m; vr[1] = s2;                 vi[1] = 0.0;
    return 2;
  }
  int mm = -m;
  idx[0] = l - mm; vr[0] = 0.0; vi[0] = s2;
  idx[1] = l + mm; vr[1] = 0.0; vi[1] = (mm & 1) ? s2 : -s2;  // -i*(-1)^mm*s2
  return 2;
}

__device__ double w3j_real(int l1, int l2, int l3, int a, int b, int c) {
  int i1[2], i2[2], i3[2];
  double r1[2], s1[2], r2[2], s2v[2], r3[2], s3[2];
  int n1 = qrow(l1, a, i1, r1, s1);
  int n2 = qrow(l2, b, i2, r2, s2v);
  int n3 = qrow(l3, c, i3, r3, s3);
  double re = 0.0;
  for (int x = 0; x < n1; ++x)
    for (int y = 0; y < n2; ++y)
      for (int z = 0; z < n3; ++z) {
        double w = wstd(l1, l2, l3, i1[x], i2[y], i3[z]);
        if (w == 0.0) continue;
        double pr = r1[x] * r2[y] - s1[x] * s2v[y];
        double pi = r1[x] * s2v[y] + s1[x] * r2[y];
        double qr = pr * r3[z] - pi * s3[z];   // real part of triple product
        re += qr * w;
      }
  int L = l1 + l2 + l3;              // always even for our paths
  return ((L & 3) == 0) ? re : -re;  // multiply by (-i)^L (real)
}

__device__ double sh_val(int k, int col) {
  const double PI_ = 3.14159265358979323846;
  double sgn = (k == 0 || k == 3) ? 1.0 : -1.0;  // sign of x*y for the 4 dirs
  if (col == 0) return 0.5 / sqrt(PI_);
  if (col == 1) return sgn * 0.25 * sqrt(15.0 / PI_);
  if (col == 3) return -0.25 * sqrt(5.0 / PI_);  // 0.25*sqrt(5/pi)*(3z^2-1), z=0
  return 0.0;                                     // yz, xz, x^2-y^2 vanish (z=0, |x|=|y|)
}

__global__ void eq_setup(const float* __restrict__ w_agg, const float* __restrict__ w_tp,
                         const int* __restrict__ ph, const int* __restrict__ pw,
                         float* __restrict__ out, long long tail_off) {
  int gid = blockIdx.x * 256 + threadIdx.x;
  if (gid == 0) {
    out[tail_off]     = (float)(ph[0] * 4);
    out[tail_off + 1] = (float)(pw[0] * 4);
  }
  if (gid < 10648) {  // TP tensor: one thread per (a,b,c)
    int a = gid / 484;
    int r = gid - a * 484;
    int b = r / 22;
    int c = r - b * 22;
    int l1 = (a < 9) ? 4 : 6, l2 = (b < 9) ? 4 : 6, l3 = (c < 9) ? 4 : 6;
    int a_ = (a < 9) ? a : a - 9, b_ = (b < 9) ? b : b - 9, c_ = (c < 9) ? c : c - 9;
    int idx = ((l1 == 6) ? 4 : 0) + ((l2 == 6) ? 2 : 0) + ((l3 == 6) ? 1 : 0);
    double alpha = sqrt((double)(2 * l3 + 1) / 4.0);
    double v = w3j_real(l1, l2, l3, a_, b_, c_);
    g_W[(b * 22 + c) * 24 + a] = (float)((double)w_tp[idx] * alpha * v);
    if (a == 0) { g_W[(b * 22 + c) * 24 + 22] = 0.f; g_W[(b * 22 + c) * 24 + 23] = 0.f; }
  } else if (gid < 10648 + 1936) {  // AGG matrices: one thread per (k,a,c)
    int g = gid - 10648;
    int k = g / 484;
    int r = g - k * 484;
    int a = r / 22;
    int c = r - a * 22;
    int l1 = (a < 9) ? 4 : 6, l3 = (c < 9) ? 4 : 6;
    int a_ = (a < 9) ? a : a - 9, c_ = (c < 9) ? c : c - 9;
    double acc = 0.0;
    double alpha = sqrt((double)(2 * l3 + 1) / 3.0);
    if (l1 == l3) {  // l2=0 paths: (4,0,4)->w_agg[0], (6,0,6)->w_agg[3]
      int i = (l1 == 4) ? 0 : 3;
      acc += (double)w_agg[i] * alpha * sh_val(k, 0) * w3j_real(l1, 0, l3, a_, 0, c_);
    }
    {  // l2=2 paths: (4,2,4)->1, (4,2,6)->2, (6,2,4)->4, (6,2,6)->5
      int i = (l1 == 4) ? ((l3 == 4) ? 1 : 2) : ((l3 == 4) ? 4 : 5);
      double s = 0.0;
      for (int bb = 0; bb < 5; ++bb) {
        double shv = sh_val(k, 1 + bb);
        if (shv != 0.0) s += shv * w3j_real(l1, 2, l3, a_, bb, c_);
      }
      acc += (double)w_agg[i] * alpha * s;
    }
    g_M[(k * 22 + a) * 24 + c] = (float)acc;
    if (c == 0) { g_M[(k * 22 + a) * 24 + 22] = 0.f; g_M[(k * 22 + a) * 24 + 23] = 0.f; }
  }
}

// ---------------- main kernel: 64 coarse cells / block, 4 threads / cell ----
__global__ __launch_bounds__(256, 2) void eq_main(
    const float* __restrict__ f4, const float* __restrict__ f6,
    const int* __restrict__ ph, const int* __restrict__ pw,
    float* __restrict__ out) {
  const int H = ph[0], W = pw[0];
  const int Wr = W << 2;
  const long long HW = (long long)H * W;
  const long long cell0 = (long long)blockIdx.x * 64;
  if (cell0 >= HW) return;
  const int cy = (int)(cell0 / W);
  const int cx0 = (int)(cell0 - (long long)cy * W);
  const int cy2 = min(cy + 1, H - 1);

  __shared__ float Fl[2 * 65 * 22];  // staged coarse features: [row(cy|cy2)][col 0..64][22]
  __shared__ float XV[64 * 89];      // per-cell: 4 cls x 22 (ctx, then final v), stride 89

  // ---- P0: stage features (rows cy and cy2, cols cx0..cx0+64 clamped) ----
  for (int e = threadIdx.x; e < 2 * 65 * 22; e += 256) {
    int r = e / (65 * 22);
    int rem = e - r * (65 * 22);
    int col = rem / 22;
    int a = rem - col * 22;
    int px = min(cx0 + col, W - 1);
    long long p = (long long)(r ? cy2 : cy) * W + px;
    Fl[e] = (a < 9) ? f4[p * 9 + a] : f6[p * 13 + (a - 9)];
  }
  __syncthreads();

  const int cell = threadIdx.x >> 2;
  const int cls  = threadIdx.x & 3;  // bit0 = right-edge (x%4==3), bit1 = bottom (y%4==3)

  // ---- P1: context for (cell, cls): ctx = sum_k M_k * F_sel(k,cls) ----
  float ctx[22];
#pragma unroll
  for (int c = 0; c < 22; ++c) ctx[c] = 0.f;
  for (int k = 0; k < 4; ++k) {  // k: (dh,dw) = (k>>1, k&1)
    int r2 = (k >> 1) & (cls >> 1) & 1;
    int c2 = k & cls & 1;
    const float* fp = &Fl[(r2 * 65 + cell + c2) * 22];
    float f[22];
#pragma unroll
    for (int a = 0; a < 22; ++a) f[a] = fp[a];
    const float* mbase = &g_M[k * 22 * 24];
#pragma unroll
    for (int a = 0; a < 22; ++a) {
#pragma unroll
      for (int c = 0; c < 22; ++c) ctx[c] = fmaf(f[a], mbase[a * 24 + c], ctx[c]);
    }
  }
  {
    float* cp = &XV[cell * 89 + cls * 22];
#pragma unroll
    for (int c = 0; c < 22; ++c) cp[c] = ctx[c];
  }
  __syncthreads();

  // ---- P2: TP, c-split across the 4 threads of a cell ----
  float F[22];
  {
    const float* fp = &Fl[cell * 22];  // center = row cy, own col
#pragma unroll
    for (int a = 0; a < 22; ++a) F[a] = fp[a];
  }
  const int c0  = (cls == 0) ? 0 : (cls == 1) ? 6 : (cls == 2) ? 12 : 17;
  const int csz = (cls < 2) ? 6 : 5;
  float oacc[4][6];
#pragma unroll
  for (int q = 0; q < 4; ++q)
#pragma unroll
    for (int j = 0; j < 6; ++j) oacc[q][j] = 0.f;

  const float* xbase = &XV[cell * 89];
  for (int b = 0; b < 22; ++b) {
    float t[6];
#pragma unroll
    for (int j = 0; j < 6; ++j) {
      float tv = 0.f;
      if (j < csz) {
        const float* wrow = &g_W[(b * 22 + c0 + j) * 24];
#pragma unroll
        for (int a = 0; a < 22; ++a) tv = fmaf(F[a], wrow[a], tv);
      }
      t[j] = tv;
    }
    float q0 = xbase[b];
    float q1 = xbase[22 + b];
    float q2 = xbase[44 + b];
    float q3 = xbase[66 + b];
#pragma unroll
    for (int j = 0; j < 6; ++j) {
      oacc[0][j] = fmaf(q0, t[j], oacc[0][j]);
      oacc[1][j] = fmaf(q1, t[j], oacc[1][j]);
      oacc[2][j] = fmaf(q2, t[j], oacc[2][j]);
      oacc[3][j] = fmaf(q3, t[j], oacc[3][j]);
    }
  }
  __syncthreads();  // everyone done reading ctx before XV is overwritten

  // ---- epilogue: v = out + F (residual), store per-class vectors ----
#pragma unroll
  for (int q = 0; q < 4; ++q) {
    float* vp = &XV[cell * 89 + q * 22 + c0];
#pragma unroll
    for (int j = 0; j < 6; ++j) {
      if (j < csz) vp[j] = oacc[q][j] + F[c0 + j];
    }
  }
  __syncthreads();

  // ---- write phase: thread t <-> HR pixel column x = 4*cx0 + t ----
  const long long N = HW * 16;
  float* out6 = out + N * 9;
  const int x   = (cx0 << 2) + threadIdx.x;
  const int cw  = threadIdx.x >> 2;
  const int pxm = threadIdx.x & 3;
#pragma unroll
  for (int ry = 0; ry < 4; ++ry) {
    const int y = (cy << 2) + ry;
    const int clsw = ((ry == 3) ? 2 : 0) | ((pxm == 3) ? 1 : 0);
    const float* v = &XV[cw * 89 + clsw * 22];
    long long n = (long long)y * Wr + x;
    float* o4 = out + n * 9;
#pragma unroll
    for (int ch = 0; ch < 9; ++ch) o4[ch] = v[ch];
    float* o6 = out6 + n * 13;
#pragma unroll
    for (int ch = 0; ch < 13; ++ch) o6[ch] = v[9 + ch];
  }
}

extern "C" void kernel_launch(void* const* d_in, const int* in_sizes, int n_in,
                              void* d_out, int out_size, void* d_ws, size_t ws_size,
                              hipStream_t stream) {
  const float* f4   = (const float*)d_in[0];
  const float* f6   = (const float*)d_in[1];
  const int*   ph   = (const int*)d_in[2];
  const int*   pw   = (const int*)d_in[3];
  const float* wagg = (const float*)d_in[4];
  const float* wtp  = (const float*)d_in[5];
  float* out = (float*)d_out;

  long long HW = in_sizes[0] / 9;           // coarse pixel count
  long long tail = (long long)out_size - 2; // (Hr, Wr) slot

  eq_setup<<<50, 256, 0, stream>>>(wagg, wtp, ph, pw, out, tail);
  int nblocks = (int)((HW + 63) / 64);
  eq_main<<<nblocks, 256, 0, stream>>>(f4, f6, ph, pw, out);
}

// Round 2
// 97.353 us; speedup vs baseline: 2.7682x; 2.7682x over previous
//
#include <hip/hip_runtime.h>
#include <hip/hip_bf16.h>
#include <math.h>

typedef __attribute__((ext_vector_type(8))) short short8;
typedef __attribute__((ext_vector_type(4))) float f32x4;
typedef __attribute__((ext_vector_type(4))) unsigned int u32x4;

// ---------------- factorial tables (fp64) -------------------------
__constant__ double c_fact[20] = {
    1.0, 1.0, 2.0, 6.0, 24.0, 120.0, 720.0, 5040.0, 40320.0, 362880.0,
    3628800.0, 39916800.0, 479001600.0, 6227020800.0, 87178291200.0,
    1307674368000.0, 20922789888000.0, 355687428096000.0,
    6402373705728000.0, 121645100408832000.0};
__constant__ double c_invf[20] = {
    1.0, 1.0, 0.5, 0.16666666666666666, 0.041666666666666664,
    0.008333333333333333, 0.001388888888888889, 1.984126984126984e-4,
    2.48015873015873e-5, 2.755731922398589e-6, 2.755731922398589e-7,
    2.505210838544172e-8, 2.08767569878681e-9, 1.6059043836821613e-10,
    1.1470745597729725e-11, 7.647163731819816e-13, 4.779477332387385e-14,
    2.8114572543455206e-15, 1.5619206968586225e-16, 8.22063524662433e-18};

__device__ double cgd(int j1, int m1, int j2, int m2, int j3, int m3) {
  if (m1 + m2 != m3) return 0.0;
  double pre = (double)(2 * j3 + 1) * c_fact[j1 + j2 - j3] * c_fact[j1 - j2 + j3] *
               c_fact[-j1 + j2 + j3] * c_invf[j1 + j2 + j3 + 1];
  pre *= c_fact[j1 + m1] * c_fact[j1 - m1] * c_fact[j2 + m2] * c_fact[j2 - m2] *
         c_fact[j3 + m3] * c_fact[j3 - m3];
  int kmin = max(0, max(j2 - j3 - m1, j1 - j3 + m2));
  int kmax = min(j1 + j2 - j3, min(j1 - m1, j2 + m2));
  double s = 0.0;
  for (int k = kmin; k <= kmax; ++k) {
    double d = c_invf[k] * c_invf[j1 + j2 - j3 - k] * c_invf[j1 - m1 - k] *
               c_invf[j2 + m2 - k] * c_invf[j3 - j2 + m1 + k] * c_invf[j3 - j1 - m2 + k];
    s += ((k & 1) ? -d : d);
  }
  return sqrt(pre) * s;
}

__device__ double wstd(int l1, int l2, int l3, int i, int j, int k) {
  int m1 = i - l1, m2 = j - l2, m3 = k - l3;
  if (m1 + m2 + m3 != 0) return 0.0;
  int e = l1 - l2 - m3;
  double sgn = (e & 1) ? -1.0 : 1.0;
  return sgn / sqrt((double)(2 * l3 + 1)) * cgd(l1, m1, l2, m2, l3, -m3);
}

__device__ int qrow(int l, int a, int idx[2], double vr[2], double vi[2]) {
  const double s2 = 0.70710678118654752440;
  int m = a - l;
  if (m == 0) { idx[0] = l; vr[0] = 1.0; vi[0] = 0.0; return 1; }
  if (m > 0) {
    idx[0] = l + m; vr[0] = (m & 1) ? -s2 : s2; vi[0] = 0.0;
    idx[1] = l - m; vr[1] = s2;                 vi[1] = 0.0;
    return 2;
  }
  int mm = -m;
  idx[0] = l - mm; vr[0] = 0.0; vi[0] = s2;
  idx[1] = l + mm; vr[1] = 0.0; vi[1] = (mm & 1) ? s2 : -s2;
  return 2;
}

__device__ double w3j_real(int l1, int l2, int l3, int a, int b, int c) {
  int i1[2], i2[2], i3[2];
  double r1[2], s1[2], r2[2], s2v[2], r3[2], s3[2];
  int n1 = qrow(l1, a, i1, r1, s1);
  int n2 = qrow(l2, b, i2, r2, s2v);
  int n3 = qrow(l3, c, i3, r3, s3);
  double re = 0.0;
  for (int x = 0; x < n1; ++x)
    for (int y = 0; y < n2; ++y)
      for (int z = 0; z < n3; ++z) {
        double w = wstd(l1, l2, l3, i1[x], i2[y], i3[z]);
        if (w == 0.0) continue;
        double pr = r1[x] * r2[y] - s1[x] * s2v[y];
        double pi = r1[x] * s2v[y] + s1[x] * r2[y];
        double qr = pr * r3[z] - pi * s3[z];
        re += qr * w;
      }
  int L = l1 + l2 + l3;
  return ((L & 3) == 0) ? re : -re;
}

__device__ double sh_val(int k, int col) {
  const double PI_ = 3.14159265358979323846;
  double sgn = (k == 0 || k == 3) ? 1.0 : -1.0;
  if (col == 0) return 0.5 / sqrt(PI_);
  if (col == 1) return sgn * 0.25 * sqrt(15.0 / PI_);
  if (col == 3) return -0.25 * sqrt(5.0 / PI_);
  return 0.0;
}

// ws float layout: [0,10648) Wfold[a*484+b*22+c] ; [10648,12584) Mfold[k*484+a*22+c]
// then ushort: W3G[22528] frag-swizzled ; M3G[4096]
__global__ void eq_setup1(const float* __restrict__ w_agg, const float* __restrict__ w_tp,
                          const int* __restrict__ ph, const int* __restrict__ pw,
                          float* __restrict__ out, long long tail_off,
                          float* __restrict__ ws) {
  int gid = blockIdx.x * 256 + threadIdx.x;
  if (gid == 0) {
    out[tail_off]     = (float)(ph[0] * 4);
    out[tail_off + 1] = (float)(pw[0] * 4);
  }
  float* Wfold = ws;
  float* Mfold = ws + 10648;
  if (gid < 10648) {  // TP tensor: one thread per (a,b,c)
    int a = gid / 484;
    int r = gid - a * 484;
    int b = r / 22;
    int c = r - b * 22;
    int l1 = (a < 9) ? 4 : 6, l2 = (b < 9) ? 4 : 6, l3 = (c < 9) ? 4 : 6;
    int a_ = (a < 9) ? a : a - 9, b_ = (b < 9) ? b : b - 9, c_ = (c < 9) ? c : c - 9;
    int idx = ((l1 == 6) ? 4 : 0) + ((l2 == 6) ? 2 : 0) + ((l3 == 6) ? 1 : 0);
    double alpha = sqrt((double)(2 * l3 + 1) / 4.0);
    double v = w3j_real(l1, l2, l3, a_, b_, c_);
    Wfold[a * 484 + b * 22 + c] = (float)((double)w_tp[idx] * alpha * v);
  } else if (gid < 10648 + 1936) {  // AGG: one thread per (k,a,c)
    int g = gid - 10648;
    int k = g / 484;
    int r = g - k * 484;
    int a = r / 22;
    int c = r - a * 22;
    int l1 = (a < 9) ? 4 : 6, l3 = (c < 9) ? 4 : 6;
    int a_ = (a < 9) ? a : a - 9, c_ = (c < 9) ? c : c - 9;
    double acc = 0.0;
    double alpha = sqrt((double)(2 * l3 + 1) / 3.0);
    if (l1 == l3) {
      int i = (l1 == 4) ? 0 : 3;
      acc += (double)w_agg[i] * alpha * sh_val(k, 0) * w3j_real(l1, 0, l3, a_, 0, c_);
    }
    {
      int i = (l1 == 4) ? ((l3 == 4) ? 1 : 2) : ((l3 == 4) ? 4 : 5);
      double s = 0.0;
      for (int bb = 0; bb < 5; ++bb) {
        double shv = sh_val(k, 1 + bb);
        if (shv != 0.0) s += shv * w3j_real(l1, 2, l3, a_, bb, c_);
      }
      acc += (double)w_agg[i] * alpha * s;
    }
    Mfold[k * 484 + a * 22 + c] = (float)acc;
  }
}

// swizzle Wfold/Mfold into MFMA B-fragment order (bf16)
__global__ void eq_setup2(float* __restrict__ ws) {
  const float* Wfold = ws;
  const float* Mfold = ws + 10648;
  unsigned short* W3G = (unsigned short*)(ws + 12584);
  unsigned short* M3G = W3G + 22528;
  int gid = blockIdx.x * 256 + threadIdx.x;
  if (gid < 22528) {
    int a = gid >> 10;            // 1024 per a
    int rem = gid & 1023;
    int nt = rem >> 9;
    int l = (rem >> 3) & 63;
    int e = rem & 7;
    int b = ((l >> 4) << 3) + e;  // k index
    int c = nt * 16 + (l & 15);
    float v = (b < 22 && c < 22) ? Wfold[a * 484 + b * 22 + c] : 0.f;
    __hip_bfloat16 h = __float2bfloat16(v);
    W3G[gid] = __builtin_bit_cast(unsigned short, h);
  } else if (gid < 22528 + 4096) {
    int s = gid - 22528;
    int km = s >> 10;
    int rem = s & 1023;
    int nt = rem >> 9;
    int l = (rem >> 3) & 63;
    int e = rem & 7;
    int a = ((l >> 4) << 3) + e;  // k index
    int c = nt * 16 + (l & 15);
    float v = (a < 22 && c < 22) ? Mfold[km * 484 + a * 22 + c] : 0.f;
    __hip_bfloat16 h = __float2bfloat16(v);
    M3G[s] = __builtin_bit_cast(unsigned short, h);
  }
}

__device__ __forceinline__ short bf16rn(float x) {
  __hip_bfloat16 h = __float2bfloat16(x);
  return (short)__builtin_bit_cast(unsigned short, h);
}

// ---------------- main kernel: 16 cells (64 rows) / block, 256 threads ----
__global__ __launch_bounds__(256, 2) void eq_main(
    const float* __restrict__ f4, const float* __restrict__ f6,
    const int* __restrict__ ph, const int* __restrict__ pw,
    const float* __restrict__ ws, float* __restrict__ out) {
  const int H = ph[0], Wc = pw[0];
  const int bx = (Wc + 15) >> 4;
  if ((long long)blockIdx.x >= (long long)bx * H) return;
  const int y0 = blockIdx.x / bx;
  const int x0 = (blockIdx.x - y0 * bx) << 4;

  __shared__ __align__(16) float Fs[2 * 17 * 24];          // 3264 B
  __shared__ __align__(16) float CtxV[64 * 28];            // 7168 B (ctx then vout)
  __shared__ __align__(16) unsigned short W3s[22 * 1024];  // 45056 B
  __shared__ __align__(16) unsigned short M3s[4 * 1024];   // 8192 B

  // ---- stage B-fragments (linear) ----
  {
    const u32x4* srcW = (const u32x4*)(ws + 12584);
    u32x4* dstW = (u32x4*)W3s;
    for (int i = threadIdx.x; i < 2816; i += 256) dstW[i] = srcW[i];
    const u32x4* srcM = srcW + 2816;
    u32x4* dstM = (u32x4*)M3s;
    for (int i = threadIdx.x; i < 512; i += 256) dstM[i] = srcM[i];
  }
  // ---- stage coarse features: rows y0,y0+1 x cols x0..x0+16, 24-padded ----
  for (int e = threadIdx.x; e < 2 * 17 * 24; e += 256) {
    int r = e / 408;
    int rem = e - r * 408;
    int col = rem / 24;
    int a = rem - col * 24;
    float v = 0.f;
    int yy = min(y0 + r, H - 1);
    int xx = min(x0 + col, Wc - 1);
    long long p = (long long)yy * Wc + xx;
    if (a < 22) v = (a < 9) ? f4[p * 9 + a] : f6[p * 13 + (a - 9)];
    Fs[e] = v;
  }
  // zero ctx pad cols 22,23 (read by b0=16 fragment)
  for (int e = threadIdx.x; e < 64; e += 256) {
    CtxV[e * 28 + 22] = 0.f;
    CtxV[e * 28 + 23] = 0.f;
  }
  __syncthreads();

  const int wv = threadIdx.x >> 6;  // wave id: 16 rows each
  const int l = threadIdx.x & 63;
  const int l15 = l & 15;
  const int lg = l >> 4;            // 0..3
  const int q = l15 & 3;
  const int cellA = (wv << 2) + (l15 >> 2);  // cell of this lane's A-row
  const int cellD = (wv << 2) + lg;          // cell of this lane's D-rows
  const int a0 = lg << 3;                    // fragment k-offset: 0,8,16,24

  // ---- K1: ctx = sum_k X_k * M_k  (MFMA, K=22 padded to 32) ----
  f32x4 cacc0 = {0.f, 0.f, 0.f, 0.f}, cacc1 = {0.f, 0.f, 0.f, 0.f};
#pragma unroll
  for (int km = 0; km < 4; ++km) {
    short8 av = (short8)0;
    if (a0 < 24) {
      int dy = (km >> 1) & (q >> 1);
      int dx = km & q & 1;
      const f32x4* fp = (const f32x4*)&Fs[(dy * 17 + cellA + dx) * 24 + a0];
      f32x4 lo = fp[0], hi = fp[1];
      av[0] = bf16rn(lo[0]); av[1] = bf16rn(lo[1]); av[2] = bf16rn(lo[2]); av[3] = bf16rn(lo[3]);
      av[4] = bf16rn(hi[0]); av[5] = bf16rn(hi[1]); av[6] = bf16rn(hi[2]); av[7] = bf16rn(hi[3]);
    }
    const short8 b0v = *(const short8*)&M3s[(km * 2 + 0) * 512 + l * 8];
    const short8 b1v = *(const short8*)&M3s[(km * 2 + 1) * 512 + l * 8];
    cacc0 = __builtin_amdgcn_mfma_f32_16x16x32_bf16(av, b0v, cacc0, 0, 0, 0);
    cacc1 = __builtin_amdgcn_mfma_f32_16x16x32_bf16(av, b1v, cacc1, 0, 0, 0);
  }
  // write ctx (wave-local rows)
#pragma unroll
  for (int r = 0; r < 4; ++r) {
    int row = wv * 16 + (lg << 2) + r;
    CtxV[row * 28 + l15] = cacc0[r];
    if (l15 < 6) CtxV[row * 28 + 16 + l15] = cacc1[r];
  }

  // ---- K2 A-source: this lane's ctx row (8 floats at b0=a0) ----
  float cv0 = 0.f, cv1 = 0.f, cv2 = 0.f, cv3 = 0.f, cv4 = 0.f, cv5 = 0.f, cv6 = 0.f, cv7 = 0.f;
  if (a0 < 24) {
    const f32x4* cp = (const f32x4*)&CtxV[(wv * 16 + l15) * 28 + a0];
    f32x4 lo = cp[0], hi = cp[1];
    cv0 = lo[0]; cv1 = lo[1]; cv2 = lo[2]; cv3 = lo[3];
    cv4 = hi[0]; cv5 = hi[1]; cv6 = hi[2]; cv7 = hi[3];
  }

  // ---- K2: out = sum_a F[a] * (ctx . W[a])  -- F folded into A-frag ----
  f32x4 oacc0 = {0.f, 0.f, 0.f, 0.f}, oacc1 = {0.f, 0.f, 0.f, 0.f};
#pragma unroll 2
  for (int a = 0; a < 22; ++a) {
    float Fv = Fs[cellA * 24 + a];
    short8 av;
    av[0] = bf16rn(cv0 * Fv); av[1] = bf16rn(cv1 * Fv);
    av[2] = bf16rn(cv2 * Fv); av[3] = bf16rn(cv3 * Fv);
    av[4] = bf16rn(cv4 * Fv); av[5] = bf16rn(cv5 * Fv);
    av[6] = bf16rn(cv6 * Fv); av[7] = bf16rn(cv7 * Fv);
    const short8 w0 = *(const short8*)&W3s[(a * 2 + 0) * 512 + l * 8];
    const short8 w1 = *(const short8*)&W3s[(a * 2 + 1) * 512 + l * 8];
    oacc0 = __builtin_amdgcn_mfma_f32_16x16x32_bf16(av, w0, oacc0, 0, 0, 0);
    oacc1 = __builtin_amdgcn_mfma_f32_16x16x32_bf16(av, w1, oacc1, 0, 0, 0);
  }

  // ---- epilogue: vout = out + residual F (reuse CtxV; wave-local rows) ----
  {
    float r0 = Fs[cellD * 24 + l15];
    float r1 = (l15 < 6) ? Fs[cellD * 24 + 16 + l15] : 0.f;
#pragma unroll
    for (int r = 0; r < 4; ++r) {
      int row = wv * 16 + (lg << 2) + r;
      CtxV[row * 28 + l15] = oacc0[r] + r0;
      if (l15 < 6) CtxV[row * 28 + 16 + l15] = oacc1[r] + r1;
    }
  }
  __syncthreads();

  // ---- coalesced writer: wave wv handles HR row y0*4+wv ----
  {
    const int Wr = Wc << 2;
    const long long Npix = (long long)H * Wc * 16;
    float* out6 = out + Npix * 9;
    const int ry = wv;
    const long long y4 = (long long)(y0 << 2) + ry;
    const long long base4 = y4 * Wr + ((long long)x0 << 2);
    const int xmax = min(16, Wc - x0) << 2;
    const int qy = (ry == 3) ? 2 : 0;
#pragma unroll
    for (int s = 0; s < 9; ++s) {
      int idx = s * 64 + l;
      int px = idx / 9;
      int ch = idx - px * 9;
      if (px < xmax) {
        int cl = px >> 2;
        int qq = qy | (((px & 3) == 3) ? 1 : 0);
        out[base4 * 9 + idx] = CtxV[(cl * 4 + qq) * 28 + ch];
      }
    }
#pragma unroll
    for (int s = 0; s < 13; ++s) {
      int idx = s * 64 + l;
      int px = idx / 13;
      int ch = idx - px * 13;
      if (px < xmax) {
        int cl = px >> 2;
        int qq = qy | (((px & 3) == 3) ? 1 : 0);
        out6[base4 * 13 + idx] = CtxV[(cl * 4 + qq) * 28 + 9 + ch];
      }
    }
  }
}

extern "C" void kernel_launch(void* const* d_in, const int* in_sizes, int n_in,
                              void* d_out, int out_size, void* d_ws, size_t ws_size,
                              hipStream_t stream) {
  const float* f4 = (const float*)d_in[0];
  const float* f6 = (const float*)d_in[1];
  const int* ph = (const int*)d_in[2];
  const int* pw = (const int*)d_in[3];
  const float* wagg = (const float*)d_in[4];
  const float* wtp = (const float*)d_in[5];
  float* out = (float*)d_out;
  float* wsf = (float*)d_ws;

  long long HW = (long long)in_sizes[0] / 9;
  long long tail = (long long)out_size - 2;

  eq_setup1<<<50, 256, 0, stream>>>(wagg, wtp, ph, pw, out, tail, wsf);
  eq_setup2<<<104, 256, 0, stream>>>(wsf);

  int S = (int)(sqrt((double)HW) + 0.5);
  long long nb;
  if ((long long)S * S == HW) {
    nb = (long long)((S + 15) / 16) * S;  // square image (the bench case)
  } else {
    nb = HW / 16 + HW + 1;  // conservative cover for any H*W split
  }
  eq_main<<<(int)nb, 256, 0, stream>>>(f4, f6, ph, pw, wsf, out);
}

// Round 3
// 66.587 us; speedup vs baseline: 4.0471x; 1.4620x over previous
//
#include <hip/hip_runtime.h>
#include <hip/hip_bf16.h>
#include <math.h>

typedef __attribute__((ext_vector_type(8))) short short8;
typedef __attribute__((ext_vector_type(4))) float f32x4;

// ---------------- factorial tables (fp64) -------------------------
__constant__ double c_fact[20] = {
    1.0, 1.0, 2.0, 6.0, 24.0, 120.0, 720.0, 5040.0, 40320.0, 362880.0,
    3628800.0, 39916800.0, 479001600.0, 6227020800.0, 87178291200.0,
    1307674368000.0, 20922789888000.0, 355687428096000.0,
    6402373705728000.0, 121645100408832000.0};
__constant__ double c_invf[20] = {
    1.0, 1.0, 0.5, 0.16666666666666666, 0.041666666666666664,
    0.008333333333333333, 0.001388888888888889, 1.984126984126984e-4,
    2.48015873015873e-5, 2.755731922398589e-6, 2.755731922398589e-7,
    2.505210838544172e-8, 2.08767569878681e-9, 1.6059043836821613e-10,
    1.1470745597729725e-11, 7.647163731819816e-13, 4.779477332387385e-14,
    2.8114572543455206e-15, 1.5619206968586225e-16, 8.22063524662433e-18};

__device__ double cgd(int j1, int m1, int j2, int m2, int j3, int m3) {
  if (m1 + m2 != m3) return 0.0;
  double pre = (double)(2 * j3 + 1) * c_fact[j1 + j2 - j3] * c_fact[j1 - j2 + j3] *
               c_fact[-j1 + j2 + j3] * c_invf[j1 + j2 + j3 + 1];
  pre *= c_fact[j1 + m1] * c_fact[j1 - m1] * c_fact[j2 + m2] * c_fact[j2 - m2] *
         c_fact[j3 + m3] * c_fact[j3 - m3];
  int kmin = max(0, max(j2 - j3 - m1, j1 - j3 + m2));
  int kmax = min(j1 + j2 - j3, min(j1 - m1, j2 + m2));
  double s = 0.0;
  for (int k = kmin; k <= kmax; ++k) {
    double d = c_invf[k] * c_invf[j1 + j2 - j3 - k] * c_invf[j1 - m1 - k] *
               c_invf[j2 + m2 - k] * c_invf[j3 - j2 + m1 + k] * c_invf[j3 - j1 - m2 + k];
    s += ((k & 1) ? -d : d);
  }
  return sqrt(pre) * s;
}

__device__ double wstd(int l1, int l2, int l3, int i, int j, int k) {
  int m1 = i - l1, m2 = j - l2, m3 = k - l3;
  if (m1 + m2 + m3 != 0) return 0.0;
  int e = l1 - l2 - m3;
  double sgn = (e & 1) ? -1.0 : 1.0;
  return sgn / sqrt((double)(2 * l3 + 1)) * cgd(l1, m1, l2, m2, l3, -m3);
}

__device__ int qrow(int l, int a, int idx[2], double vr[2], double vi[2]) {
  const double s2 = 0.70710678118654752440;
  int m = a - l;
  if (m == 0) { idx[0] = l; vr[0] = 1.0; vi[0] = 0.0; return 1; }
  if (m > 0) {
    idx[0] = l + m; vr[0] = (m & 1) ? -s2 : s2; vi[0] = 0.0;
    idx[1] = l - m; vr[1] = s2;                 vi[1] = 0.0;
    return 2;
  }
  int mm = -m;
  idx[0] = l - mm; vr[0] = 0.0; vi[0] = s2;
  idx[1] = l + mm; vr[1] = 0.0; vi[1] = (mm & 1) ? s2 : -s2;
  return 2;
}

__device__ double w3j_real(int l1, int l2, int l3, int a, int b, int c) {
  int i1[2], i2[2], i3[2];
  double r1[2], s1[2], r2[2], s2v[2], r3[2], s3[2];
  int n1 = qrow(l1, a, i1, r1, s1);
  int n2 = qrow(l2, b, i2, r2, s2v);
  int n3 = qrow(l3, c, i3, r3, s3);
  double re = 0.0;
  for (int x = 0; x < n1; ++x)
    for (int y = 0; y < n2; ++y)
      for (int z = 0; z < n3; ++z) {
        double w = wstd(l1, l2, l3, i1[x], i2[y], i3[z]);
        if (w == 0.0) continue;
        double pr = r1[x] * r2[y] - s1[x] * s2v[y];
        double pi = r1[x] * s2v[y] + s1[x] * r2[y];
        double qr = pr * r3[z] - pi * s3[z];
        re += qr * w;
      }
  int L = l1 + l2 + l3;
  return ((L & 3) == 0) ? re : -re;
}

__device__ double sh_val(int k, int col) {
  const double PI_ = 3.14159265358979323846;
  double sgn = (k == 0 || k == 3) ? 1.0 : -1.0;
  if (col == 0) return 0.5 / sqrt(PI_);
  if (col == 1) return sgn * 0.25 * sqrt(15.0 / PI_);
  if (col == 3) return -0.25 * sqrt(5.0 / PI_);
  return 0.0;
}

__device__ __forceinline__ unsigned short bf16u(float x) {
  __hip_bfloat16 h = __float2bfloat16(x);
  return __builtin_bit_cast(unsigned short, h);
}
__device__ __forceinline__ float b2f(unsigned short u) {
  unsigned int v = ((unsigned int)u) << 16;
  return __builtin_bit_cast(float, v);
}

// ws layout (ushort): [0,22528) W3G frag-swizzled ; [22528,26624) M3G
__global__ void eq_setup(const float* __restrict__ w_agg, const float* __restrict__ w_tp,
                         const int* __restrict__ ph, const int* __restrict__ pw,
                         float* __restrict__ out, long long tail_off,
                         unsigned short* __restrict__ ws) {
  int gid = blockIdx.x * 256 + threadIdx.x;
  if (gid == 0) {
    out[tail_off]     = (float)(ph[0] * 4);
    out[tail_off + 1] = (float)(pw[0] * 4);
  }
  if (gid < 22528) {  // W3G: B-fragment element for K2
    int a = gid >> 10;
    int rem = gid & 1023;
    int nt = rem >> 9;
    int l = (rem >> 3) & 63;
    int e = rem & 7;
    int b = ((l >> 4) << 3) + e;   // k index (contraction over b)
    int c = nt * 16 + (l & 15);    // output col
    float v = 0.f;
    if (b < 22 && c < 22) {
      int l1 = (a < 9) ? 4 : 6, l2 = (b < 9) ? 4 : 6, l3 = (c < 9) ? 4 : 6;
      int a_ = (a < 9) ? a : a - 9, b_ = (b < 9) ? b : b - 9, c_ = (c < 9) ? c : c - 9;
      int idx = ((l1 == 6) ? 4 : 0) + ((l2 == 6) ? 2 : 0) + ((l3 == 6) ? 1 : 0);
      double alpha = sqrt((double)(2 * l3 + 1) / 4.0);
      v = (float)((double)w_tp[idx] * alpha * w3j_real(l1, l2, l3, a_, b_, c_));
    }
    ws[gid] = bf16u(v);
  } else if (gid < 26624) {  // M3G: B-fragment element for K1
    int s = gid - 22528;
    int km = s >> 10;
    int rem = s & 1023;
    int nt = rem >> 9;
    int l = (rem >> 3) & 63;
    int e = rem & 7;
    int a = ((l >> 4) << 3) + e;   // k index (contraction over a)
    int c = nt * 16 + (l & 15);    // output col
    float v = 0.f;
    if (a < 22 && c < 22) {
      int l1 = (a < 9) ? 4 : 6, l3 = (c < 9) ? 4 : 6;
      int a_ = (a < 9) ? a : a - 9, c_ = (c < 9) ? c : c - 9;
      double acc = 0.0;
      double alpha = sqrt((double)(2 * l3 + 1) / 3.0);
      if (l1 == l3) {
        int i = (l1 == 4) ? 0 : 3;
        acc += (double)w_agg[i] * alpha * sh_val(km, 0) * w3j_real(l1, 0, l3, a_, 0, c_);
      }
      {
        int i = (l1 == 4) ? ((l3 == 4) ? 1 : 2) : ((l3 == 4) ? 4 : 5);
        double t = 0.0;
        for (int bb = 0; bb < 5; ++bb) {
          double shv = sh_val(km, 1 + bb);
          if (shv != 0.0) t += shv * w3j_real(l1, 2, l3, a_, bb, c_);
        }
        acc += (double)w_agg[i] * alpha * t;
      }
      v = (float)acc;
    }
    ws[gid] = bf16u(v);
  }
}

__device__ __forceinline__ void load_lds16(const unsigned int* g, unsigned int* l) {
  __builtin_amdgcn_global_load_lds(
      (const __attribute__((address_space(1))) unsigned int*)g,
      (__attribute__((address_space(3))) unsigned int*)l, 16, 0, 0);
}

// ---------------- main kernel: 32 cells / block, 512 threads (8 waves) ----
__global__ __launch_bounds__(512, 4) void eq_main(
    const float* __restrict__ f4, const float* __restrict__ f6,
    const int* __restrict__ ph, const int* __restrict__ pw,
    const unsigned short* __restrict__ ws, float* __restrict__ out) {
  const int H = ph[0], Wc = pw[0];
  const int bx = (Wc + 31) >> 5;
  if ((long long)blockIdx.x >= (long long)bx * H) return;
  const int y0 = blockIdx.x / bx;
  const int x0 = (blockIdx.x - y0 * bx) << 5;

  __shared__ __align__(16) unsigned short WM[26624];   // W3s [0,22528) + M3s [22528,26624)
  __shared__ __align__(16) unsigned short FsB[1584];   // 2 rows x 33 cols x 24 (bf16)
  __shared__ __align__(16) unsigned short CtxV[4096];  // 128 rows x 32 (bf16): ctx then vout

  const int tid = threadIdx.x;
  const int wv = tid >> 6;
  const int l = tid & 63;

  // ---- stage WM via async global->LDS (linear, 16B/lane) ----
  {
    const unsigned int* src = (const unsigned int*)ws;
    unsigned int* dstbase = (unsigned int*)WM;
#pragma unroll
    for (int i = 0; i < 7; ++i) {
      int chunk0 = i * 512 + wv * 64;          // wave-uniform
      if (chunk0 < 3328) {
        load_lds16(src + (chunk0 + l) * 4, dstbase + chunk0 * 4);
      }
    }
  }
  // ---- stage coarse features as bf16 (rows y0,y0+1, cols x0..x0+32) ----
  for (int e = tid; e < 1584; e += 512) {
    int r = e / 792;
    int rem = e - r * 792;
    int col = rem / 24;
    int a = rem - col * 24;
    float v = 0.f;
    int yy = min(y0 + r, H - 1);
    int xx = min(x0 + col, Wc - 1);
    long long p = (long long)yy * Wc + xx;
    if (a < 22) v = (a < 9) ? f4[p * 9 + a] : f6[p * 13 + (a - 9)];
    FsB[e] = bf16u(v);
  }
  __syncthreads();

  const int l15 = l & 15;
  const int lg = l >> 4;
  const int q = l15 & 3;
  const int cellA = (wv << 2) + (l15 >> 2);  // cell of this lane's A-row
  const int cellD = (wv << 2) + lg;          // cell of this lane's D-rows
  const int a0 = lg << 3;                    // k-offset: 0,8,16,24

  // ---- K1: ctx = sum_k X_k * M_k ----
  f32x4 c0 = {0.f, 0.f, 0.f, 0.f}, c1 = {0.f, 0.f, 0.f, 0.f};
#pragma unroll
  for (int km = 0; km < 4; ++km) {
    short8 av = (short8)0;
    if (a0 < 24) {
      int dy = (km >> 1) & (q >> 1);
      int dx = km & q & 1;
      av = *(const short8*)&FsB[(dy * 33 + cellA + dx) * 24 + a0];
    }
    const short8 b0 = *(const short8*)&WM[22528 + (km * 2 + 0) * 512 + l * 8];
    const short8 b1 = *(const short8*)&WM[22528 + (km * 2 + 1) * 512 + l * 8];
    c0 = __builtin_amdgcn_mfma_f32_16x16x32_bf16(av, b0, c0, 0, 0, 0);
    c1 = __builtin_amdgcn_mfma_f32_16x16x32_bf16(av, b1, c1, 0, 0, 0);
  }
  // write ctx (bf16, own wave's rows) + zero pad cols 22,23
#pragma unroll
  for (int r = 0; r < 4; ++r) {
    int row = wv * 16 + (lg << 2) + r;
    CtxV[row * 32 + l15] = bf16u(c0[r]);
    if (l15 < 6) CtxV[row * 32 + 16 + l15] = bf16u(c1[r]);
    else if (l15 < 8) CtxV[row * 32 + 16 + l15] = 0;
  }

  // ---- hoist F row (22 regs) and ctx fragment ----
  float Fv[22];
  {
    const short8 f0 = *(const short8*)&FsB[cellA * 24 + 0];
    const short8 f1 = *(const short8*)&FsB[cellA * 24 + 8];
    const short8 f2 = *(const short8*)&FsB[cellA * 24 + 16];
#pragma unroll
    for (int j = 0; j < 8; ++j) {
      Fv[j] = b2f((unsigned short)f0[j]);
      Fv[8 + j] = b2f((unsigned short)f1[j]);
      if (j < 6) Fv[16 + j] = b2f((unsigned short)f2[j]);
    }
  }
  float cv[8];
  {
    short8 cvb = (short8)0;
    if (a0 < 24) cvb = *(const short8*)&CtxV[(wv * 16 + l15) * 32 + a0];
#pragma unroll
    for (int j = 0; j < 8; ++j) cv[j] = b2f((unsigned short)cvb[j]);
  }

  // ---- K2: out = sum_a F[a] * (ctx . W[a]) ; even/odd dual accumulators ----
  f32x4 oE0 = {0.f, 0.f, 0.f, 0.f}, oE1 = {0.f, 0.f, 0.f, 0.f};
  f32x4 oO0 = {0.f, 0.f, 0.f, 0.f}, oO1 = {0.f, 0.f, 0.f, 0.f};
#pragma unroll
  for (int ap = 0; ap < 11; ++ap) {
    {
      const int a = 2 * ap;
      const float s = Fv[a];
      short8 av;
#pragma unroll
      for (int j = 0; j < 8; ++j) av[j] = (short)bf16u(cv[j] * s);
      const short8 w0 = *(const short8*)&WM[a * 1024 + l * 8];
      const short8 w1 = *(const short8*)&WM[a * 1024 + 512 + l * 8];
      oE0 = __builtin_amdgcn_mfma_f32_16x16x32_bf16(av, w0, oE0, 0, 0, 0);
      oE1 = __builtin_amdgcn_mfma_f32_16x16x32_bf16(av, w1, oE1, 0, 0, 0);
    }
    {
      const int a = 2 * ap + 1;
      const float s = Fv[a];
      short8 av;
#pragma unroll
      for (int j = 0; j < 8; ++j) av[j] = (short)bf16u(cv[j] * s);
      const short8 w0 = *(const short8*)&WM[a * 1024 + l * 8];
      const short8 w1 = *(const short8*)&WM[a * 1024 + 512 + l * 8];
      oO0 = __builtin_amdgcn_mfma_f32_16x16x32_bf16(av, w0, oO0, 0, 0, 0);
      oO1 = __builtin_amdgcn_mfma_f32_16x16x32_bf16(av, w1, oO1, 0, 0, 0);
    }
  }

  // ---- epilogue: vout = out + residual F (bf16, own wave's rows) ----
  {
    const float r0 = b2f(FsB[cellD * 24 + l15]);
    const float r1 = (l15 < 6) ? b2f(FsB[cellD * 24 + 16 + l15]) : 0.f;
#pragma unroll
    for (int r = 0; r < 4; ++r) {
      int row = wv * 16 + (lg << 2) + r;
      CtxV[row * 32 + l15] = bf16u(oE0[r] + oO0[r] + r0);
      if (l15 < 6) CtxV[row * 32 + 16 + l15] = bf16u(oE1[r] + oO1[r] + r1);
    }
  }
  __syncthreads();

  // ---- coalesced writer: wave wv -> HR row (wv>>1), x-half (wv&1) ----
  {
    const int Wr = Wc << 2;
    const long long Npix = (long long)H * Wc * 16;
    float* out6 = out + Npix * 9;
    const int ry = wv >> 1;
    const int h = wv & 1;
    const long long y4 = (long long)(y0 << 2) + ry;
    const int xbase = (x0 << 2) + (h << 6);        // local-to-global HR x of element 0
    const int xmax = (min(32, Wc - x0) << 2);      // valid local px count in block
    const int qy = (ry == 3) ? 2 : 0;
    const long long b4 = ((long long)y4 * Wr + xbase) * 9;
    const long long b6 = ((long long)y4 * Wr + xbase) * 13;
#pragma unroll
    for (int s = 0; s < 9; ++s) {
      int idx = s * 64 + l;
      int pxh = idx / 9;              // px within this half (0..63)
      int ch = idx - pxh * 9;
      int px = (h << 6) + pxh;        // px within block (0..127)
      if (px < xmax) {
        int cl = px >> 2;
        int qq = qy | (((px & 3) == 3) ? 1 : 0);
        out[b4 + idx] = b2f(CtxV[((cl << 2) + qq) * 32 + ch]);
      }
    }
#pragma unroll
    for (int s = 0; s < 13; ++s) {
      int idx = s * 64 + l;
      int pxh = idx / 13;
      int ch = idx - pxh * 13;
      int px = (h << 6) + pxh;
      if (px < xmax) {
        int cl = px >> 2;
        int qq = qy | (((px & 3) == 3) ? 1 : 0);
        out6[b6 + idx] = b2f(CtxV[((cl << 2) + qq) * 32 + 9 + ch]);
      }
    }
  }
}

extern "C" void kernel_launch(void* const* d_in, const int* in_sizes, int n_in,
                              void* d_out, int out_size, void* d_ws, size_t ws_size,
                              hipStream_t stream) {
  const float* f4 = (const float*)d_in[0];
  const float* f6 = (const float*)d_in[1];
  const int* ph = (const int*)d_in[2];
  const int* pw = (const int*)d_in[3];
  const float* wagg = (const float*)d_in[4];
  const float* wtp = (const float*)d_in[5];
  float* out = (float*)d_out;
  unsigned short* wsu = (unsigned short*)d_ws;

  long long HW = (long long)in_sizes[0] / 9;
  long long tail = (long long)out_size - 2;

  eq_setup<<<104, 256, 0, stream>>>(wagg, wtp, ph, pw, out, tail, wsu);

  int S = (int)(sqrt((double)HW) + 0.5);
  long long nb;
  if ((long long)S * S == HW) {
    nb = (long long)((S + 31) / 32) * S;  // square image (the bench case)
  } else {
    nb = HW;  // conservative cover; excess blocks exit on the bx*H bound
  }
  eq_main<<<(int)nb, 512, 0, stream>>>(f4, f6, ph, pw, wsu, out);
}